// Round 1
// baseline (1047.143 us; speedup 1.0000x reference)
//
#include <hip/hip_runtime.h>
#include <math.h>

#define NV 10000
#define ND 300
#define NB 64
#define NL 128
#define CFv 5.0f
#define EPSV 1e-8f

// ws float-index layout
#define WS_CTX   0        // 300 floats: context
#define WS_CN    300      // 1 float: ||context||
#define WS_CNT   301      // 1 int: active-row count
#define WS_COS   320      // 10000 floats: |cos|
#define WS_ROWS  10320    // 8192 ints: compacted active row ids (b*128+l)
#define WS_S     18512    // 8192 floats: softmax denominators per compacted row
// total = 26704 floats = 106816 bytes

__global__ __launch_bounds__(256) void k_init(float* __restrict__ out, float* __restrict__ wsf) {
  int g = blockIdx.x * 256 + threadIdx.x;
  if (g < NB * ND) out[g] = 0.f;
  if (g < 302) wsf[g] = 0.f;   // zero context, cn, count
}

__global__ __launch_bounds__(320) void k_context(const int* __restrict__ clist,
                                                 const int* __restrict__ clen,
                                                 const float* __restrict__ embed,
                                                 float* __restrict__ wsf) {
  __shared__ int kl[NL];
  int b = blockIdx.x, d = threadIdx.x;
  int len = clen[b];
  if (d < NL) kl[d] = clist[b * NL + d];
  __syncthreads();
  if (d >= ND) return;
  float acc = 0.f;
  for (int l = 0; l < len; ++l)
    acc += embed[(long)kl[l] * ND + d];
  float dn = (float)(len > 0 ? len : 1);
  atomicAdd(&wsf[WS_CTX + d], acc * (1.0f / NB) / dn);
}

__global__ __launch_bounds__(320) void k_cn(float* __restrict__ wsf) {
  __shared__ float red[5];
  int t = threadIdx.x;
  float x = (t < ND) ? wsf[WS_CTX + t] : 0.f;
  float s = x * x;
  #pragma unroll
  for (int o = 32; o; o >>= 1) s += __shfl_xor(s, o);
  if ((t & 63) == 0) red[t >> 6] = s;
  __syncthreads();
  if (t == 0) {
    float tot = 0.f;
    #pragma unroll
    for (int i = 0; i < 5; ++i) tot += red[i];
    wsf[WS_CN] = sqrtf(tot);
  }
}

__global__ __launch_bounds__(256) void k_cos(const float* __restrict__ cw, float* __restrict__ wsf) {
  int wid = threadIdx.x >> 6, lane = threadIdx.x & 63;
  int v = blockIdx.x * 4 + wid;
  const float* row = cw + (long)v * ND;
  float dot = 0.f, rn2 = 0.f;
  for (int d = lane; d < ND; d += 64) {
    float w = row[d], c = wsf[WS_CTX + d];
    dot += w * c;
    rn2 += w * w;
  }
  #pragma unroll
  for (int o = 32; o; o >>= 1) { dot += __shfl_xor(dot, o); rn2 += __shfl_xor(rn2, o); }
  if (lane == 0) {
    float cn = wsf[WS_CN];
    wsf[WS_COS + v] = fabsf(dot) / fmaxf(cn * sqrtf(rn2), EPSV);
  }
}

__global__ __launch_bounds__(256) void k_compact(const int* __restrict__ clen, int* __restrict__ wsi) {
  int t = blockIdx.x * 256 + threadIdx.x;   // 0..8191
  int b = t >> 7, l = t & 127;
  if (l < clen[b]) {
    int pos = atomicAdd(&wsi[WS_CNT], 1);
    wsi[WS_ROWS + pos] = t;
  }
}

// softmax denominator per active row (full K range)
__global__ __launch_bounds__(256) void k_srow(const int* __restrict__ clist,
                                              const float* __restrict__ edge,
                                              const float* __restrict__ aff,
                                              const float* __restrict__ lam,
                                              float* __restrict__ wsf) {
  const int* wsi = (const int*)wsf;
  int wid = threadIdx.x >> 6, lane = threadIdx.x & 63;
  int pos = blockIdx.x * 4 + wid;
  int count = wsi[WS_CNT];
  if (pos >= count) return;
  int row = wsi[WS_ROWS + pos];
  long koff = (long)clist[row] * NV;
  float sp = 0.f;
  for (int v = lane; v < NV; v += 64) {
    float em = edge[koff + v];
    float lv = lam[v];
    float w = lv * em * wsf[WS_COS + v] + (1.f - lv) * ((em > 0.f) ? aff[v] : 0.f);
    sp += __expf(CFv * w);
  }
  #pragma unroll
  for (int o = 32; o; o >>= 1) sp += __shfl_xor(sp, o);
  if (lane == 0) wsf[WS_S + pos] = sp;
}

#define KC 32
#define KSEG 2496   // 4 K-segments: 2496,2496,2496,2512 (all chunk-of-32 friendly, mult of 4)

__global__ __launch_bounds__(256) void k_main(const int* __restrict__ clist,
                                              const int* __restrict__ clen,
                                              const float* __restrict__ cw,
                                              const float* __restrict__ edge,
                                              const float* __restrict__ aff,
                                              const float* __restrict__ lam,
                                              const float* __restrict__ wsf,
                                              float* __restrict__ out) {
  __shared__ float Wl[KC][ND];   // 38400 B
  __shared__ float el[KC][32];   // 4096 B
  __shared__ int   rowbuf[32];
  __shared__ float scl[32];
  const int* wsi = (const int*)wsf;
  int tid = threadIdx.x;
  int count = wsi[WS_CNT];
  int rb = blockIdx.x >> 2, ks = blockIdx.x & 3;
  int r0 = rb * 32;
  if (r0 >= count) return;
  int vstart = KSEG * ks;
  int vend = (ks == 3) ? NV : vstart + KSEG;

  if (tid < 32) {
    int p = r0 + tid;
    int row = (p < count) ? wsi[WS_ROWS + p] : -1;
    rowbuf[tid] = row;
    float sc = 0.f;
    if (row >= 0) {
      float s = wsf[WS_S + p];
      int lenb = clen[row >> 7];
      float dn = (float)(lenb > 0 ? lenb : 1);
      if (s > 0.f) sc = 1.0f / (s * dn);
    }
    scl[tid] = sc;
  }
  __syncthreads();

  // staging mapping: thread -> (row sr, 4 consecutive k's)
  int sr = tid >> 3;          // 0..31
  int k4 = tid & 7;           // kk0 = 4*k4
  int srow_id = rowbuf[sr];
  long koff = (srow_id >= 0) ? (long)clist[srow_id] * NV : -1;

  // compute mapping: lane tn covers cols {4tn..4tn+3, 256+tn(<300)}, tm covers rows 8tm..8tm+7
  int tn = tid & 63, tm = tid >> 6;
  int dxi = 256 + ((tn < ND - 256) ? tn : 0);
  float acc[8][5];
  #pragma unroll
  for (int i = 0; i < 8; ++i)
    #pragma unroll
    for (int h = 0; h < 5; ++h) acc[i][h] = 0.f;

  const float4* cw4 = (const float4*)cw;

  for (int v0 = vstart; v0 < vend; v0 += KC) {
    int kc = min(KC, vend - v0);
    // stage W tile (zero-pad kk >= kc)
    for (int q = tid; q < KC * (ND / 4); q += 256) {
      int kk = q / (ND / 4);
      int p  = q - kk * (ND / 4);
      float4 w4 = make_float4(0.f, 0.f, 0.f, 0.f);
      if (kk < kc) w4 = cw4[(long)(v0 + kk) * (ND / 4) + p];
      *(float4*)&Wl[kk][4 * p] = w4;
    }
    // stage e tile
    {
      int kk0 = 4 * k4;
      float e0 = 0.f, e1 = 0.f, e2 = 0.f, e3 = 0.f;
      if (koff >= 0 && kk0 < kc) {
        int v = v0 + kk0;
        float4 em4 = *(const float4*)&edge[koff + v];
        float4 c4  = *(const float4*)&wsf[WS_COS + v];
        float4 l4  = *(const float4*)&lam[v];
        float4 a4  = *(const float4*)&aff[v];
        e0 = __expf(CFv * (l4.x * em4.x * c4.x + (1.f - l4.x) * ((em4.x > 0.f) ? a4.x : 0.f)));
        e1 = __expf(CFv * (l4.y * em4.y * c4.y + (1.f - l4.y) * ((em4.y > 0.f) ? a4.y : 0.f)));
        e2 = __expf(CFv * (l4.z * em4.z * c4.z + (1.f - l4.z) * ((em4.z > 0.f) ? a4.z : 0.f)));
        e3 = __expf(CFv * (l4.w * em4.w * c4.w + (1.f - l4.w) * ((em4.w > 0.f) ? a4.w : 0.f)));
      }
      el[kk0 + 0][sr] = e0;
      el[kk0 + 1][sr] = e1;
      el[kk0 + 2][sr] = e2;
      el[kk0 + 3][sr] = e3;
    }
    __syncthreads();
    #pragma unroll 8
    for (int kk = 0; kk < KC; ++kk) {
      float4 ea = *(const float4*)&el[kk][8 * tm];
      float4 eb = *(const float4*)&el[kk][8 * tm + 4];
      float4 w4 = *(const float4*)&Wl[kk][4 * tn];
      float  w5 = Wl[kk][dxi];
      float e[8] = {ea.x, ea.y, ea.z, ea.w, eb.x, eb.y, eb.z, eb.w};
      float w[5] = {w4.x, w4.y, w4.z, w4.w, w5};
      #pragma unroll
      for (int i = 0; i < 8; ++i)
        #pragma unroll
        for (int h = 0; h < 5; ++h)
          acc[i][h] = fmaf(e[i], w[h], acc[i][h]);
    }
    __syncthreads();
  }

  // output: merge consecutive rows sharing the same batch b to cut atomics ~8x
  int curb = -1;
  float os0 = 0.f, os1 = 0.f, os2 = 0.f, os3 = 0.f, os4 = 0.f;
  #pragma unroll
  for (int i = 0; i < 8; ++i) {
    int r = 8 * tm + i;
    int row = rowbuf[r];
    float sc = scl[r];
    int b = (row >= 0 && sc > 0.f) ? (row >> 7) : -1;
    if (b != curb) {
      if (curb >= 0) {
        float* ob = out + curb * ND;
        atomicAdd(&ob[4 * tn + 0], os0);
        atomicAdd(&ob[4 * tn + 1], os1);
        atomicAdd(&ob[4 * tn + 2], os2);
        atomicAdd(&ob[4 * tn + 3], os3);
        if (tn < ND - 256) atomicAdd(&ob[256 + tn], os4);
      }
      curb = b;
      os0 = os1 = os2 = os3 = os4 = 0.f;
    }
    if (b >= 0) {
      os0 += acc[i][0] * sc;
      os1 += acc[i][1] * sc;
      os2 += acc[i][2] * sc;
      os3 += acc[i][3] * sc;
      os4 += acc[i][4] * sc;
    }
  }
  if (curb >= 0) {
    float* ob = out + curb * ND;
    atomicAdd(&ob[4 * tn + 0], os0);
    atomicAdd(&ob[4 * tn + 1], os1);
    atomicAdd(&ob[4 * tn + 2], os2);
    atomicAdd(&ob[4 * tn + 3], os3);
    if (tn < ND - 256) atomicAdd(&ob[256 + tn], os4);
  }
}

extern "C" void kernel_launch(void* const* d_in, const int* in_sizes, int n_in,
                              void* d_out, int out_size, void* d_ws, size_t ws_size,
                              hipStream_t stream) {
  const int*   clist = (const int*)d_in[0];
  const int*   clen  = (const int*)d_in[1];
  const float* embed = (const float*)d_in[2];
  const float* cw    = (const float*)d_in[3];
  const float* edge  = (const float*)d_in[4];
  const float* aff   = (const float*)d_in[5];
  const float* lam   = (const float*)d_in[6];
  float* out = (float*)d_out;
  float* wsf = (float*)d_ws;
  int*   wsi = (int*)d_ws;

  hipLaunchKernelGGL(k_init,    dim3(77),          dim3(256), 0, stream, out, wsf);
  hipLaunchKernelGGL(k_context, dim3(NB),          dim3(320), 0, stream, clist, clen, embed, wsf);
  hipLaunchKernelGGL(k_cn,      dim3(1),           dim3(320), 0, stream, wsf);
  hipLaunchKernelGGL(k_cos,     dim3(NV / 4),      dim3(256), 0, stream, cw, wsf);
  hipLaunchKernelGGL(k_compact, dim3(NB * NL / 256), dim3(256), 0, stream, clen, wsi);
  hipLaunchKernelGGL(k_srow,    dim3(NB * NL / 4), dim3(256), 0, stream, clist, edge, aff, lam, wsf);
  hipLaunchKernelGGL(k_main,    dim3(4 * NB * NL / 32), dim3(256), 0, stream,
                     clist, clen, cw, edge, aff, lam, wsf, out);
}

// Round 2
// 492.356 us; speedup vs baseline: 2.1268x; 2.1268x over previous
//
#include <hip/hip_runtime.h>
#include <math.h>

#define NV 10000
#define ND 300
#define NB 64
#define NL 128
#define CFv 5.0f
#define EPSV 1e-8f

// ws float-index layout (total 26704 floats = 106816 B, proven <= ws_size in round 1)
#define WS_CTX   0        // 300 floats
#define WS_CN    300      // 1 float
#define WS_CNT   301      // 1 int (active-row count)
#define WS_COS   320      // 10000 floats
#define WS_ROWS  10320    // 8192 ints (compacted, SORTED active row ids b*128+l)
#define WS_S     18512    // 8192 floats (softmax denominators per compacted row)

// k_main config
#define KR   160          // K-slice per block
#define KRP  168          // padded row length (bf16) -> 336 B stride, ~2-way banks
#define NKR  63           // ceil(10000/160)
#define GMG  8            // M-group interleave
#define NTI  19           // 19 n-tiles of 16 cover 304 >= 300
#define MT   32           // rows per M-tile
#define QS   (MT*42)      // e-stage float4 slots (42 = KRP/4)

typedef __attribute__((ext_vector_type(8))) __bf16 bf16x8;
typedef __attribute__((ext_vector_type(4))) float f32x4;

static __device__ __forceinline__ unsigned short f2bf(float x) {
  union { float f; unsigned u; } v; v.f = x;
  unsigned r = v.u + 0x7fffu + ((v.u >> 16) & 1u);
  return (unsigned short)(r >> 16);
}

__global__ __launch_bounds__(256) void k_init(float* __restrict__ out, float* __restrict__ wsf) {
  int g = blockIdx.x * 256 + threadIdx.x;
  if (g < NB * ND) out[g] = 0.f;
  if (g < 302) wsf[g] = 0.f;
}

__global__ __launch_bounds__(320) void k_context(const int* __restrict__ clist,
                                                 const int* __restrict__ clen,
                                                 const float* __restrict__ embed,
                                                 float* __restrict__ wsf) {
  __shared__ int kl[NL];
  int b = blockIdx.x, d = threadIdx.x;
  int len = clen[b];
  if (d < NL) kl[d] = clist[b * NL + d];
  __syncthreads();
  if (d >= ND) return;
  float acc = 0.f;
  for (int l = 0; l < len; ++l)
    acc += embed[(long)kl[l] * ND + d];
  float dn = (float)(len > 0 ? len : 1);
  atomicAdd(&wsf[WS_CTX + d], acc * (1.0f / NB) / dn);
}

__global__ __launch_bounds__(320) void k_cn(float* __restrict__ wsf) {
  __shared__ float red[5];
  int t = threadIdx.x;
  float x = (t < ND) ? wsf[WS_CTX + t] : 0.f;
  float s = x * x;
  #pragma unroll
  for (int o = 32; o; o >>= 1) s += __shfl_xor(s, o);
  if ((t & 63) == 0) red[t >> 6] = s;
  __syncthreads();
  if (t == 0) {
    float tot = 0.f;
    #pragma unroll
    for (int i = 0; i < 5; ++i) tot += red[i];
    wsf[WS_CN] = sqrtf(tot);
  }
}

__global__ __launch_bounds__(256) void k_cos(const float* __restrict__ cw, float* __restrict__ wsf) {
  int wid = threadIdx.x >> 6, lane = threadIdx.x & 63;
  int v = blockIdx.x * 4 + wid;
  const float* row = cw + (long)v * ND;
  float dot = 0.f, rn2 = 0.f;
  for (int d = lane; d < ND; d += 64) {
    float w = row[d], c = wsf[WS_CTX + d];
    dot += w * c;
    rn2 += w * w;
  }
  #pragma unroll
  for (int o = 32; o; o >>= 1) { dot += __shfl_xor(dot, o); rn2 += __shfl_xor(rn2, o); }
  if (lane == 0) {
    float cn = wsf[WS_CN];
    wsf[WS_COS + v] = fabsf(dot) / fmaxf(cn * sqrtf(rn2), EPSV);
  }
}

// deterministic, SORTED compaction via per-batch prefix sums
__global__ __launch_bounds__(256) void k_compact(const int* __restrict__ clen, int* __restrict__ wsi) {
  __shared__ int cum[NB + 1];
  int tid = threadIdx.x;
  if (tid == 0) {
    int c = 0;
    for (int b = 0; b < NB; ++b) {
      cum[b] = c;
      int ln = clen[b]; if (ln < 0) ln = 0; if (ln > NL) ln = NL;
      c += ln;
    }
    cum[NB] = c;
    wsi[WS_CNT] = c;
  }
  __syncthreads();
  for (int t = tid; t < NB * NL; t += 256) {
    int b = t >> 7, l = t & 127;
    int len = cum[b + 1] - cum[b];
    if (l < len) wsi[WS_ROWS + cum[b] + l] = t;
  }
}

// softmax denominators per compacted row (full-K streaming pass, float4)
__global__ __launch_bounds__(256) void k_srow(const int* __restrict__ clist,
                                              const float* __restrict__ edge,
                                              const float* __restrict__ aff,
                                              const float* __restrict__ lam,
                                              float* __restrict__ wsf) {
  const int* wsi = (const int*)wsf;
  int wid = threadIdx.x >> 6, lane = threadIdx.x & 63;
  int pos = blockIdx.x * 4 + wid;
  int count = wsi[WS_CNT];
  if (pos >= count) return;
  int row = wsi[WS_ROWS + pos];
  const float4* e4 = (const float4*)(edge + (long)clist[row] * NV);
  const float4* c4 = (const float4*)(wsf + WS_COS);
  const float4* l4 = (const float4*)lam;
  const float4* a4 = (const float4*)aff;
  float sp = 0.f;
  for (int v = lane; v < NV / 4; v += 64) {
    float4 em = e4[v], co = c4[v], la = l4[v], af = a4[v];
    sp += __expf(CFv * (la.x * em.x * co.x + (1.f - la.x) * ((em.x > 0.f) ? af.x : 0.f)));
    sp += __expf(CFv * (la.y * em.y * co.y + (1.f - la.y) * ((em.y > 0.f) ? af.y : 0.f)));
    sp += __expf(CFv * (la.z * em.z * co.z + (1.f - la.z) * ((em.z > 0.f) ? af.z : 0.f)));
    sp += __expf(CFv * (la.w * em.w * co.w + (1.f - la.w) * ((em.w > 0.f) ? af.w : 0.f)));
  }
  #pragma unroll
  for (int o = 32; o; o >>= 1) sp += __shfl_xor(sp, o);
  if (lane == 0) wsf[WS_S + pos] = sp;
}

// K-major MFMA GEMM: block owns K-slice [v0,v0+klen), W-tile resident in LDS,
// loops over M-tiles (32 rows each, stride GMG), e computed on the fly.
__global__ __launch_bounds__(512) void k_main(const int* __restrict__ clist,
                                              const int* __restrict__ clen,
                                              const float* __restrict__ cw,
                                              const float* __restrict__ edge,
                                              const float* __restrict__ aff,
                                              const float* __restrict__ lam,
                                              const float* __restrict__ wsf,
                                              float* __restrict__ out) {
  __shared__ unsigned short Wt[304][KRP];       // 102144 B  (Wt[n][k] = bf16 W[v0+k][n])
  __shared__ unsigned short ebuf[2][MT][KRP];   //  21504 B
  __shared__ float cls[3][KRP];                 //   2016 B  (cos/lam/aff slice)
  __shared__ int   rb_s[2][MT];
  __shared__ float scl_s[2][MT];

  const int* wsi = (const int*)wsf;
  int tid = threadIdx.x;
  int count = wsi[WS_CNT];
  int Mtiles = (count + MT - 1) / MT;
  int kr = blockIdx.x / GMG, g = blockIdx.x % GMG;
  int v0 = kr * KR;
  int klen = NV - v0; if (klen > KR) klen = KR;
  int nch = (klen + 31) >> 5;

  // stage cos/lam/aff slice
  for (int q = tid; q < 3 * KRP; q += 512) {
    int a = q / KRP, k = q - a * KRP;
    float val = 0.f;
    if (v0 + k < NV)
      val = (a == 0) ? wsf[WS_COS + v0 + k] : (a == 1) ? lam[v0 + k] : aff[v0 + k];
    cls[a][k] = val;
  }
  // zero W-tile (covers n/k padding)
  for (int q = tid; q < 304 * KRP / 8; q += 512)
    ((uint4*)&Wt[0][0])[q] = make_uint4(0u, 0u, 0u, 0u);
  __syncthreads();
  // fill W-tile transposed, f32 -> bf16
  {
    const float4* cw4 = (const float4*)cw;
    for (int q = tid; q < klen * 75; q += 512) {
      int kk = q / 75, p = q - kk * 75;
      float4 w = cw4[(long)(v0 + kk) * 75 + p];
      Wt[4 * p + 0][kk] = f2bf(w.x);
      Wt[4 * p + 1][kk] = f2bf(w.y);
      Wt[4 * p + 2][kk] = f2bf(w.z);
      Wt[4 * p + 3][kk] = f2bf(w.w);
    }
  }

  int wv = tid >> 6, lane = tid & 63;
  int q4 = lane >> 4, l15 = lane & 15;
  int nt0 = (wv * NTI) >> 3, nt1 = ((wv + 1) * NTI) >> 3;   // 2-3 n-tiles per wave

  float4 eld[3];
  int    vld[3];
  int    m_row; float m_scl;

  auto stage_load = [&](int mtx) {
    int r0 = mtx * MT;
    #pragma unroll
    for (int j = 0; j < 3; ++j) {
      vld[j] = 0;
      int q = tid + j * 512;
      if (q < QS) {
        int rm = q / 42, p4 = q - rm * 42, k = 4 * p4;
        int pos = r0 + rm;
        if (pos < count && k < klen) {
          int rowid = wsi[WS_ROWS + pos];
          eld[j] = *(const float4*)(edge + (long)clist[rowid] * NV + v0 + k);
          vld[j] = 1;
        }
      }
    }
    m_row = -1; m_scl = 0.f;
    if (tid < MT) {
      int pos = r0 + tid;
      if (pos < count) {
        int rowid = wsi[WS_ROWS + pos];
        float S = wsf[WS_S + pos];
        int ln = clen[rowid >> 7];
        m_row = rowid;
        m_scl = 1.0f / (S * (float)(ln > 0 ? ln : 1));
      }
    }
  };

  auto stage_write = [&](int nb) {
    #pragma unroll
    for (int j = 0; j < 3; ++j) {
      int q = tid + j * 512;
      if (q < QS) {
        int rm = q / 42, p4 = q - rm * 42, k = 4 * p4;
        ushort4 ev = make_ushort4(0, 0, 0, 0);
        if (vld[j]) {
          float4 co = *(const float4*)&cls[0][k];
          float4 la = *(const float4*)&cls[1][k];
          float4 af = *(const float4*)&cls[2][k];
          float4 em = eld[j];
          ev.x = f2bf(__expf(CFv * (la.x * em.x * co.x + (1.f - la.x) * ((em.x > 0.f) ? af.x : 0.f))));
          ev.y = f2bf(__expf(CFv * (la.y * em.y * co.y + (1.f - la.y) * ((em.y > 0.f) ? af.y : 0.f))));
          ev.z = f2bf(__expf(CFv * (la.z * em.z * co.z + (1.f - la.z) * ((em.z > 0.f) ? af.z : 0.f))));
          ev.w = f2bf(__expf(CFv * (la.w * em.w * co.w + (1.f - la.w) * ((em.w > 0.f) ? af.w : 0.f))));
        }
        *(ushort4*)&ebuf[nb][rm][k] = ev;
      }
    }
    if (tid < MT) { rb_s[nb][tid] = m_row; scl_s[nb][tid] = m_scl; }
  };

  // prologue: stage first M-tile into buf 0
  stage_load(g);
  stage_write(0);
  __syncthreads();

  int cb = 0;
  for (int mt = g; mt < Mtiles; mt += GMG) {
    // 1) issue next tile's global loads early (hidden under MFMA)
    stage_load(mt + GMG);

    // 2) MFMA chunks on current buffer
    f32x4 acc[2][3] = {};
    for (int c5 = 0; c5 < nch; ++c5) {
      int kb = c5 * 32 + q4 * 8;
      bf16x8 a0 = *(const bf16x8*)(const void*)&ebuf[cb][l15][kb];
      bf16x8 a1 = *(const bf16x8*)(const void*)&ebuf[cb][16 + l15][kb];
      #pragma unroll
      for (int j = 0; j < 3; ++j) {
        if (nt0 + j < nt1) {
          bf16x8 bv = *(const bf16x8*)(const void*)&Wt[(nt0 + j) * 16 + l15][kb];
          acc[0][j] = __builtin_amdgcn_mfma_f32_16x16x32_bf16(a0, bv, acc[0][j], 0, 0, 0);
          acc[1][j] = __builtin_amdgcn_mfma_f32_16x16x32_bf16(a1, bv, acc[1][j], 0, 0, 0);
        }
      }
    }

    // 3) exp + LDS write of next tile
    stage_write(cb ^ 1);

    // 4) scaled output of current tile, rows merged per batch -> atomics
    int rws[8]; float scs[8];
    #pragma unroll
    for (int ms = 0; ms < 2; ++ms)
      #pragma unroll
      for (int r = 0; r < 4; ++r) {
        int m = ms * 16 + q4 * 4 + r;
        rws[ms * 4 + r] = rb_s[cb][m];
        scs[ms * 4 + r] = scl_s[cb][m];
      }
    #pragma unroll
    for (int j = 0; j < 3; ++j) {
      if (nt0 + j < nt1) {
        int n = (nt0 + j) * 16 + l15;
        if (n < ND) {
          float sum = 0.f; int curb = -1;
          #pragma unroll
          for (int mr = 0; mr < 8; ++mr) {
            int row = rws[mr];
            if (row >= 0) {
              int b = row >> 7;
              if (b != curb) {
                if (curb >= 0) atomicAdd(&out[curb * ND + n], sum);
                curb = b; sum = 0.f;
              }
              sum += acc[mr >> 2][j][mr & 3] * scs[mr];
            }
          }
          if (curb >= 0) atomicAdd(&out[curb * ND + n], sum);
        }
      }
    }

    __syncthreads();
    cb ^= 1;
  }
}

extern "C" void kernel_launch(void* const* d_in, const int* in_sizes, int n_in,
                              void* d_out, int out_size, void* d_ws, size_t ws_size,
                              hipStream_t stream) {
  const int*   clist = (const int*)d_in[0];
  const int*   clen  = (const int*)d_in[1];
  const float* embed = (const float*)d_in[2];
  const float* cw    = (const float*)d_in[3];
  const float* edge  = (const float*)d_in[4];
  const float* aff   = (const float*)d_in[5];
  const float* lam   = (const float*)d_in[6];
  float* out = (float*)d_out;
  float* wsf = (float*)d_ws;
  int*   wsi = (int*)d_ws;

  hipLaunchKernelGGL(k_init,    dim3(77),            dim3(256), 0, stream, out, wsf);
  hipLaunchKernelGGL(k_context, dim3(NB),            dim3(320), 0, stream, clist, clen, embed, wsf);
  hipLaunchKernelGGL(k_cn,      dim3(1),             dim3(320), 0, stream, wsf);
  hipLaunchKernelGGL(k_cos,     dim3(NV / 4),        dim3(256), 0, stream, cw, wsf);
  hipLaunchKernelGGL(k_compact, dim3(1),             dim3(256), 0, stream, clen, wsi);
  hipLaunchKernelGGL(k_srow,    dim3(NB * NL / 4),   dim3(256), 0, stream, clist, edge, aff, lam, wsf);
  hipLaunchKernelGGL(k_main,    dim3(NKR * GMG),     dim3(512), 0, stream,
                     clist, clen, cw, edge, aff, lam, wsf, out);
}

// Round 3
// 227.623 us; speedup vs baseline: 4.6003x; 2.1630x over previous
//
#include <hip/hip_runtime.h>
#include <math.h>

#define NV 10000
#define ND 300
#define NB 64
#define NL 128
#define CFv 5.0f
#define EPSV 1e-8f

// ws float-index layout (total 26704 floats = 106816 B, proven fits)
#define WS_CTX   0        // 300 floats
#define WS_CN    300      // 1 float
#define WS_CNT   301      // 1 int (active-row count)
#define WS_COS   320      // 10000 floats
#define WS_ROWS  10320    // 8192 ints (compacted, SORTED active row ids b*128+l)
#define WS_S     18512    // 8192 floats (softmax denominators per compacted row)

// k_main config
#define KR   160          // K-slice per block
#define KRP  168          // padded row length (bf16)
#define NKR  63           // ceil(10000/160)
#define GMG  8            // M-groups per K-slice (contiguous chunks)
#define NTI  19           // 19 n-tiles of 16 cover 304 >= 300
#define MT   32           // rows per M-tile
#define QS   (MT*42)      // e-stage float4 slots (42 = KRP/4)
#define SOB  16           // sout batch slots

typedef __attribute__((ext_vector_type(8))) __bf16 bf16x8;
typedef __attribute__((ext_vector_type(4))) float f32x4;

static __device__ __forceinline__ unsigned short f2bf(float x) {
  union { float f; unsigned u; } v; v.f = x;
  unsigned r = v.u + 0x7fffu + ((v.u >> 16) & 1u);
  return (unsigned short)(r >> 16);
}

__global__ __launch_bounds__(256) void k_init(float* __restrict__ out, float* __restrict__ wsf) {
  int g = blockIdx.x * 256 + threadIdx.x;
  if (g < NB * ND) out[g] = 0.f;
  if (g < 302) wsf[g] = 0.f;
}

#define CSL 4
__global__ __launch_bounds__(320) void k_context(const int* __restrict__ clist,
                                                 const int* __restrict__ clen,
                                                 const float* __restrict__ embed,
                                                 float* __restrict__ wsf) {
  __shared__ int kl[NL];
  int b = blockIdx.x / CSL, sl = blockIdx.x % CSL;
  int d = threadIdx.x;
  int len = clen[b];
  if (d < NL) kl[d] = clist[b * NL + d];
  __syncthreads();
  if (d >= ND) return;
  float acc = 0.f;
  for (int l = sl; l < len; l += CSL)
    acc += embed[(long)kl[l] * ND + d];
  float dn = (float)(len > 0 ? len : 1);
  atomicAdd(&wsf[WS_CTX + d], acc * (1.0f / NB) / dn);
}

__global__ __launch_bounds__(320) void k_cn(float* __restrict__ wsf) {
  __shared__ float red[5];
  int t = threadIdx.x;
  float x = (t < ND) ? wsf[WS_CTX + t] : 0.f;
  float s = x * x;
  #pragma unroll
  for (int o = 32; o; o >>= 1) s += __shfl_xor(s, o);
  if ((t & 63) == 0) red[t >> 6] = s;
  __syncthreads();
  if (t == 0) {
    float tot = 0.f;
    #pragma unroll
    for (int i = 0; i < 5; ++i) tot += red[i];
    wsf[WS_CN] = sqrtf(tot);
  }
}

__global__ __launch_bounds__(256) void k_cos(const float* __restrict__ cw, float* __restrict__ wsf) {
  int wid = threadIdx.x >> 6, lane = threadIdx.x & 63;
  int v = blockIdx.x * 4 + wid;
  const float* row = cw + (long)v * ND;
  float dot = 0.f, rn2 = 0.f;
  for (int d = lane; d < ND; d += 64) {
    float w = row[d], c = wsf[WS_CTX + d];
    dot += w * c;
    rn2 += w * w;
  }
  #pragma unroll
  for (int o = 32; o; o >>= 1) { dot += __shfl_xor(dot, o); rn2 += __shfl_xor(rn2, o); }
  if (lane == 0) {
    float cn = wsf[WS_CN];
    wsf[WS_COS + v] = fabsf(dot) / fmaxf(cn * sqrtf(rn2), EPSV);
  }
}

// deterministic, SORTED compaction via per-batch prefix sums
__global__ __launch_bounds__(256) void k_compact(const int* __restrict__ clen, int* __restrict__ wsi) {
  __shared__ int cum[NB + 1];
  int tid = threadIdx.x;
  if (tid == 0) {
    int c = 0;
    for (int b = 0; b < NB; ++b) {
      cum[b] = c;
      int ln = clen[b]; if (ln < 0) ln = 0; if (ln > NL) ln = NL;
      c += ln;
    }
    cum[NB] = c;
    wsi[WS_CNT] = c;
  }
  __syncthreads();
  for (int t = tid; t < NB * NL; t += 256) {
    int b = t >> 7, l = t & 127;
    int len = cum[b + 1] - cum[b];
    if (l < len) wsi[WS_ROWS + cum[b] + l] = t;
  }
}

// softmax denominators per compacted row (full-K streaming pass, float4)
__global__ __launch_bounds__(256) void k_srow(const int* __restrict__ clist,
                                              const float* __restrict__ edge,
                                              const float* __restrict__ aff,
                                              const float* __restrict__ lam,
                                              float* __restrict__ wsf) {
  const int* wsi = (const int*)wsf;
  int wid = threadIdx.x >> 6, lane = threadIdx.x & 63;
  int pos = blockIdx.x * 4 + wid;
  int count = wsi[WS_CNT];
  if (pos >= count) return;
  int row = wsi[WS_ROWS + pos];
  const float4* e4 = (const float4*)(edge + (long)clist[row] * NV);
  const float4* c4 = (const float4*)(wsf + WS_COS);
  const float4* l4 = (const float4*)lam;
  const float4* a4 = (const float4*)aff;
  float sp = 0.f;
  for (int v = lane; v < NV / 4; v += 64) {
    float4 em = e4[v], co = c4[v], la = l4[v], af = a4[v];
    sp += __expf(CFv * (la.x * em.x * co.x + (1.f - la.x) * ((em.x > 0.f) ? af.x : 0.f)));
    sp += __expf(CFv * (la.y * em.y * co.y + (1.f - la.y) * ((em.y > 0.f) ? af.y : 0.f)));
    sp += __expf(CFv * (la.z * em.z * co.z + (1.f - la.z) * ((em.z > 0.f) ? af.z : 0.f)));
    sp += __expf(CFv * (la.w * em.w * co.w + (1.f - la.w) * ((em.w > 0.f) ? af.w : 0.f)));
  }
  #pragma unroll
  for (int o = 32; o; o >>= 1) sp += __shfl_xor(sp, o);
  if (lane == 0) wsf[WS_S + pos] = sp;
}

// K-major MFMA GEMM: block owns K-slice [v0,v0+klen) with W-tile LDS-resident
// (B-fragments hoisted to registers), and a CONTIGUOUS chunk of M-tiles.
// Output accumulated in LDS sout[16 batches][304], emitted once per block.
__global__ __launch_bounds__(512) void k_main(const int* __restrict__ clist,
                                              const int* __restrict__ clen,
                                              const float* __restrict__ edge,
                                              const float* __restrict__ cw,
                                              const float* __restrict__ lam,
                                              const float* __restrict__ aff,
                                              const float* __restrict__ wsf,
                                              float* __restrict__ out) {
  __shared__ unsigned short Wt[304][KRP];       // 102144 B  (Wt[n][k] = bf16 W[v0+k][n])
  __shared__ unsigned short ebuf[2][MT][KRP];   //  21504 B
  __shared__ float cls[3][KRP];                 //   2016 B
  __shared__ float sout[SOB][304];              //  19456 B
  __shared__ int   rb_s[2][MT];
  __shared__ float scl_s[2][MT];

  const int* wsi = (const int*)wsf;
  int tid = threadIdx.x;
  int count = wsi[WS_CNT];
  int Mtiles = (count + MT - 1) / MT;
  int kr = blockIdx.x / GMG, g = blockIdx.x % GMG;
  int v0 = kr * KR;
  int klen = NV - v0; if (klen > KR) klen = KR;
  int nch = (klen + 31) >> 5;
  int tpg = (Mtiles + GMG - 1) / GMG;
  int mt0 = g * tpg;
  int mt1 = min(mt0 + tpg, Mtiles);

  int b0 = 0;
  {
    int r0c = mt0 * MT;
    if (r0c < count) b0 = wsi[WS_ROWS + r0c] >> 7;
  }

  // stage cls slice + zero sout + zero Wt
  for (int q = tid; q < 3 * KRP; q += 512) {
    int a = q / KRP, k = q - a * KRP;
    float val = 0.f;
    if (v0 + k < NV)
      val = (a == 0) ? wsf[WS_COS + v0 + k] : (a == 1) ? lam[v0 + k] : aff[v0 + k];
    cls[a][k] = val;
  }
  for (int q = tid; q < SOB * 304; q += 512) ((float*)sout)[q] = 0.f;
  for (int q = tid; q < 304 * KRP / 8; q += 512)
    ((uint4*)&Wt[0][0])[q] = make_uint4(0u, 0u, 0u, 0u);
  __syncthreads();
  // fill W-tile transposed, f32 -> bf16
  {
    const float4* cw4 = (const float4*)cw;
    for (int q = tid; q < klen * 75; q += 512) {
      int kk = q / 75, p = q - kk * 75;
      float4 w = cw4[(long)(v0 + kk) * 75 + p];
      Wt[4 * p + 0][kk] = f2bf(w.x);
      Wt[4 * p + 1][kk] = f2bf(w.y);
      Wt[4 * p + 2][kk] = f2bf(w.z);
      Wt[4 * p + 3][kk] = f2bf(w.w);
    }
  }
  __syncthreads();

  int wv = tid >> 6, lane = tid & 63;
  int q4 = lane >> 4, l15 = lane & 15;
  int nt0 = (wv * NTI) >> 3, nt1 = ((wv + 1) * NTI) >> 3;

  // hoist B-fragments into registers (read Wt once per block)
  bf16x8 bfrag[3][5] = {};
  #pragma unroll
  for (int j = 0; j < 3; ++j)
    #pragma unroll
    for (int c5 = 0; c5 < 5; ++c5)
      if (nt0 + j < nt1 && c5 < nch)
        bfrag[j][c5] = *(const bf16x8*)(const void*)&Wt[(nt0 + j) * 16 + l15][c5 * 32 + q4 * 8];

  float4 eld[3];
  int    vld[3];
  int    m_row; float m_scl;

  auto stage_load = [&](int mtx) {
    int r0 = mtx * MT;
    #pragma unroll
    for (int j = 0; j < 3; ++j) {
      vld[j] = 0;
      int q = tid + j * 512;
      if (q < QS) {
        int rm = q / 42, p4 = q - rm * 42, k = 4 * p4;
        int pos = r0 + rm;
        if (pos < count && k < klen) {
          int rowid = wsi[WS_ROWS + pos];
          eld[j] = *(const float4*)(edge + (long)clist[rowid] * NV + v0 + k);
          vld[j] = 1;
        }
      }
    }
    m_row = -1; m_scl = 0.f;
    if (tid < MT) {
      int pos = r0 + tid;
      if (pos < count) {
        int rowid = wsi[WS_ROWS + pos];
        float S = wsf[WS_S + pos];
        int ln = clen[rowid >> 7];
        m_row = rowid;
        m_scl = 1.0f / (S * (float)(ln > 0 ? ln : 1));
      }
    }
  };

  auto stage_write = [&](int nb) {
    #pragma unroll
    for (int j = 0; j < 3; ++j) {
      int q = tid + j * 512;
      if (q < QS) {
        int rm = q / 42, p4 = q - rm * 42, k = 4 * p4;
        ushort4 ev = make_ushort4(0, 0, 0, 0);
        if (vld[j]) {
          float4 co = *(const float4*)&cls[0][k];
          float4 la = *(const float4*)&cls[1][k];
          float4 af = *(const float4*)&cls[2][k];
          float4 em = eld[j];
          ev.x = f2bf(__expf(CFv * (la.x * em.x * co.x + (1.f - la.x) * ((em.x > 0.f) ? af.x : 0.f))));
          ev.y = f2bf(__expf(CFv * (la.y * em.y * co.y + (1.f - la.y) * ((em.y > 0.f) ? af.y : 0.f))));
          ev.z = f2bf(__expf(CFv * (la.z * em.z * co.z + (1.f - la.z) * ((em.z > 0.f) ? af.z : 0.f))));
          ev.w = f2bf(__expf(CFv * (la.w * em.w * co.w + (1.f - la.w) * ((em.w > 0.f) ? af.w : 0.f))));
        }
        *(ushort4*)&ebuf[nb][rm][k] = ev;
      }
    }
    if (tid < MT) { rb_s[nb][tid] = m_row; scl_s[nb][tid] = m_scl; }
  };

  // run accumulator (per lane, batches non-decreasing across the chunk)
  int curb = -1;
  float rs0 = 0.f, rs1 = 0.f, rs2 = 0.f;
  auto emit = [&](int b, float s0, float s1, float s2) {
    if (b < 0) return;
    float sv0 = s0, sv1 = s1, sv2 = s2;
    #pragma unroll
    for (int j = 0; j < 3; ++j) {
      if (nt0 + j < nt1) {
        int n = (nt0 + j) * 16 + l15;
        if (n < ND) {
          float v = (j == 0) ? sv0 : (j == 1) ? sv1 : sv2;
          int rel = b - b0;
          if (rel >= 0 && rel < SOB) atomicAdd(&sout[rel][n], v);
          else atomicAdd(&out[b * ND + n], v);
        }
      }
    }
  };

  if (mt0 < mt1) {
    stage_load(mt0);
    stage_write(0);
    __syncthreads();

    int cb = 0;
    for (int mt = mt0; mt < mt1; ++mt) {
      stage_load(mt + 1);

      f32x4 acc[2][3] = {};
      #pragma unroll
      for (int c5 = 0; c5 < 5; ++c5) {
        if (c5 < nch) {
          int kb = c5 * 32 + q4 * 8;
          bf16x8 a0 = *(const bf16x8*)(const void*)&ebuf[cb][l15][kb];
          bf16x8 a1 = *(const bf16x8*)(const void*)&ebuf[cb][16 + l15][kb];
          #pragma unroll
          for (int j = 0; j < 3; ++j) {
            if (nt0 + j < nt1) {
              acc[0][j] = __builtin_amdgcn_mfma_f32_16x16x32_bf16(a0, bfrag[j][c5], acc[0][j], 0, 0, 0);
              acc[1][j] = __builtin_amdgcn_mfma_f32_16x16x32_bf16(a1, bfrag[j][c5], acc[1][j], 0, 0, 0);
            }
          }
        }
      }

      stage_write(cb ^ 1);

      // fold current tile into per-lane runs (rows ascending: ms then r)
      #pragma unroll
      for (int ms = 0; ms < 2; ++ms)
        #pragma unroll
        for (int r = 0; r < 4; ++r) {
          int m = ms * 16 + q4 * 4 + r;
          int row = rb_s[cb][m];
          if (row >= 0) {
            int b = row >> 7;
            float sc = scl_s[cb][m];
            if (b != curb) {
              emit(curb, rs0, rs1, rs2);
              curb = b; rs0 = rs1 = rs2 = 0.f;
            }
            rs0 += acc[ms][0][r] * sc;
            rs1 += acc[ms][1][r] * sc;
            rs2 += acc[ms][2][r] * sc;
          }
        }

      __syncthreads();
      cb ^= 1;
    }
    emit(curb, rs0, rs1, rs2);
  }
  __syncthreads();

  // final emission: sout -> out (skip zeros)
  for (int q = tid; q < SOB * 304; q += 512) {
    int s = q / 304, n = q - s * 304;
    float v = sout[s][n];
    if (n < ND && v != 0.f) {
      int b = b0 + s;
      if (b < NB) atomicAdd(&out[b * ND + n], v);
    }
  }
}

extern "C" void kernel_launch(void* const* d_in, const int* in_sizes, int n_in,
                              void* d_out, int out_size, void* d_ws, size_t ws_size,
                              hipStream_t stream) {
  const int*   clist = (const int*)d_in[0];
  const int*   clen  = (const int*)d_in[1];
  const float* embed = (const float*)d_in[2];
  const float* cw    = (const float*)d_in[3];
  const float* edge  = (const float*)d_in[4];
  const float* aff   = (const float*)d_in[5];
  const float* lam   = (const float*)d_in[6];
  float* out = (float*)d_out;
  float* wsf = (float*)d_ws;
  int*   wsi = (int*)d_ws;

  hipLaunchKernelGGL(k_init,    dim3(77),            dim3(256), 0, stream, out, wsf);
  hipLaunchKernelGGL(k_context, dim3(NB * CSL),      dim3(320), 0, stream, clist, clen, embed, wsf);
  hipLaunchKernelGGL(k_cn,      dim3(1),             dim3(320), 0, stream, wsf);
  hipLaunchKernelGGL(k_cos,     dim3(NV / 4),        dim3(256), 0, stream, cw, wsf);
  hipLaunchKernelGGL(k_compact, dim3(1),             dim3(256), 0, stream, clen, wsi);
  hipLaunchKernelGGL(k_srow,    dim3(NB * NL / 4),   dim3(256), 0, stream, clist, edge, aff, lam, wsf);
  hipLaunchKernelGGL(k_main,    dim3(NKR * GMG),     dim3(512), 0, stream,
                     clist, clen, edge, cw, lam, aff, wsf, out);
}

// Round 5
// 180.314 us; speedup vs baseline: 5.8073x; 1.2624x over previous
//
#include <hip/hip_runtime.h>
#include <math.h>

#define NV 10000
#define ND 300
#define NB 64
#define NL 128
#define CFv 5.0f
#define EPSV 1e-8f

// ws float-index layout (~6.3 MB used; ws proven >= 1.6 GB by harness fill)
#define WS_CTX   0        // 300 floats
#define WS_CN    300      // 1 float
#define WS_CNT   301      // 1 int (active-row count)
#define WS_A     320      // 10000 floats: CF*lam*cos
#define WS_B     10320    // 10000 floats: CF*(1-lam)*aff
#define WS_ROWS  20320    // 8192 ints (compacted, SORTED active row ids b*128+l)
#define WS_S     28512    // 8192 floats (softmax denominators)
#define WS_WTG   36704    // bf16 WtG[304][10112] (byte off 146816, 16B aligned)

// k_main config
#define KR    128         // K-slice per block
#define WTGLD 10112       // padded WtG row length (= 79*128)
#define NKR   79          // ceil(10000/128)
#define GMG   6           // M-groups per K-slice (contiguous chunks)
#define NTI   19          // 19 n-tiles of 16 cover 304
#define MT    32          // rows per M-tile
#define SOB   16          // sout batch slots

typedef __attribute__((ext_vector_type(8))) __bf16 bf16x8;
typedef __attribute__((ext_vector_type(4))) float f32x4;

static __device__ __forceinline__ unsigned short f2bf(float x) {
  union { float f; unsigned u; } v; v.f = x;
  unsigned r = v.u + 0x7fffu + ((v.u >> 16) & 1u);
  return (unsigned short)(r >> 16);
}

__global__ __launch_bounds__(256) void k_init(float* __restrict__ out, float* __restrict__ wsf) {
  int g = blockIdx.x * 256 + threadIdx.x;
  if (g < NB * ND) out[g] = 0.f;
  if (g < 302) wsf[g] = 0.f;
}

#define CSL 4
__global__ __launch_bounds__(320) void k_context(const int* __restrict__ clist,
                                                 const int* __restrict__ clen,
                                                 const float* __restrict__ embed,
                                                 float* __restrict__ wsf) {
  __shared__ int kl[NL];
  int b = blockIdx.x / CSL, sl = blockIdx.x % CSL;
  int d = threadIdx.x;
  int len = clen[b];
  if (d < NL) kl[d] = clist[b * NL + d];
  __syncthreads();
  if (d >= ND) return;
  float acc = 0.f;
  for (int l = sl; l < len; l += CSL)
    acc += embed[(long)kl[l] * ND + d];
  float dn = (float)(len > 0 ? len : 1);
  atomicAdd(&wsf[WS_CTX + d], acc * (1.0f / NB) / dn);
}

__global__ __launch_bounds__(320) void k_cn(float* __restrict__ wsf) {
  __shared__ float red[5];
  int t = threadIdx.x;
  float x = (t < ND) ? wsf[WS_CTX + t] : 0.f;
  float s = x * x;
  #pragma unroll
  for (int o = 32; o; o >>= 1) s += __shfl_xor(s, o);
  if ((t & 63) == 0) red[t >> 6] = s;
  __syncthreads();
  if (t == 0) {
    float tot = 0.f;
    #pragma unroll
    for (int i = 0; i < 5; ++i) tot += red[i];
    wsf[WS_CN] = sqrtf(tot);
  }
}

// per-concept |cos| then fused constants A = CF*lam*cos, B = CF*(1-lam)*aff
__global__ __launch_bounds__(256) void k_cos(const float* __restrict__ cw,
                                             const float* __restrict__ lam,
                                             const float* __restrict__ aff,
                                             float* __restrict__ wsf) {
  int wid = threadIdx.x >> 6, lane = threadIdx.x & 63;
  int v = blockIdx.x * 4 + wid;
  const float* row = cw + (long)v * ND;
  float dot = 0.f, rn2 = 0.f;
  for (int d = lane; d < ND; d += 64) {
    float w = row[d], c = wsf[WS_CTX + d];
    dot += w * c;
    rn2 += w * w;
  }
  #pragma unroll
  for (int o = 32; o; o >>= 1) { dot += __shfl_xor(dot, o); rn2 += __shfl_xor(rn2, o); }
  if (lane == 0) {
    float cn = wsf[WS_CN];
    float cosv = fabsf(dot) / fmaxf(cn * sqrtf(rn2), EPSV);
    float lv = lam[v];
    wsf[WS_A + v] = CFv * lv * cosv;
    wsf[WS_B + v] = CFv * (1.f - lv) * aff[v];
  }
}

// transpose concept_w -> bf16 WtG[304][WTGLD] in ws (zero-padded rows/cols)
__global__ __launch_bounds__(256) void k_wt(const float* __restrict__ cw, float* __restrict__ wsf) {
  __shared__ unsigned short T[304][68];
  int tid = threadIdx.x;
  int v0 = blockIdx.x * 64;
  for (int q = tid; q < 304 * 68 / 2; q += 256) ((unsigned*)&T[0][0])[q] = 0u;
  __syncthreads();
  const float4* cw4 = (const float4*)cw;
  for (int q = tid; q < 64 * 75; q += 256) {
    int r = q / 75, p = q - r * 75;
    int v = v0 + r;
    if (v < NV) {
      float4 w = cw4[(long)v * 75 + p];
      T[4 * p + 0][r] = f2bf(w.x);
      T[4 * p + 1][r] = f2bf(w.y);
      T[4 * p + 2][r] = f2bf(w.z);
      T[4 * p + 3][r] = f2bf(w.w);
    }
  }
  __syncthreads();
  unsigned short* wtg = (unsigned short*)(wsf + WS_WTG);
  for (int q = tid; q < 304 * 16; q += 256) {
    int n = q >> 4, rp = q & 15;
    *(ushort4*)&wtg[(long)n * WTGLD + v0 + 4 * rp] = *(const ushort4*)&T[n][4 * rp];
  }
}

// deterministic, SORTED compaction via per-batch prefix sums
__global__ __launch_bounds__(256) void k_compact(const int* __restrict__ clen, int* __restrict__ wsi) {
  __shared__ int cum[NB + 1];
  int tid = threadIdx.x;
  if (tid == 0) {
    int c = 0;
    for (int b = 0; b < NB; ++b) {
      cum[b] = c;
      int ln = clen[b]; if (ln < 0) ln = 0; if (ln > NL) ln = NL;
      c += ln;
    }
    cum[NB] = c;
    wsi[WS_CNT] = c;
  }
  __syncthreads();
  for (int t = tid; t < NB * NL; t += 256) {
    int b = t >> 7, l = t & 127;
    int len = cum[b + 1] - cum[b];
    if (l < len) wsi[WS_ROWS + cum[b] + l] = t;
  }
}

// softmax denominators per compacted row (full-K streaming pass)
__global__ __launch_bounds__(256) void k_srow(const int* __restrict__ clist,
                                              const float* __restrict__ edge,
                                              float* __restrict__ wsf) {
  const int* wsi = (const int*)wsf;
  int wid = threadIdx.x >> 6, lane = threadIdx.x & 63;
  int pos = blockIdx.x * 4 + wid;
  int count = wsi[WS_CNT];
  if (pos >= count) return;
  int row = wsi[WS_ROWS + pos];
  const float4* e4 = (const float4*)(edge + (long)clist[row] * NV);
  const float4* A4 = (const float4*)(wsf + WS_A);
  const float4* B4 = (const float4*)(wsf + WS_B);
  float sp = 0.f;
  for (int v = lane; v < NV / 4; v += 64) {
    float4 em = e4[v], a = A4[v], b = B4[v];
    sp += __expf(fmaf(a.x, em.x, (em.x > 0.f) ? b.x : 0.f));
    sp += __expf(fmaf(a.y, em.y, (em.y > 0.f) ? b.y : 0.f));
    sp += __expf(fmaf(a.z, em.z, (em.z > 0.f) ? b.z : 0.f));
    sp += __expf(fmaf(a.w, em.w, (em.w > 0.f) ? b.w : 0.f));
  }
  #pragma unroll
  for (int o = 32; o; o >>= 1) sp += __shfl_xor(sp, o);
  if (lane == 0) wsf[WS_S + pos] = sp;
}

// K-major MFMA GEMM: block owns K-slice [v0,v0+klen), B-fragments in registers
// (loaded once from pre-transposed bf16 WtG), contiguous M-chunk, LDS sout.
__global__ __launch_bounds__(512, 4) void k_main(const int* __restrict__ clist,
                                                 const int* __restrict__ clen,
                                                 const float* __restrict__ edge,
                                                 const float* __restrict__ wsf,
                                                 float* __restrict__ out) {
  __shared__ unsigned short ebuf[2][MT * KR];   // 16384 B (XOR-swizzled)
  __shared__ float cls[2][KR];                  //  1024 B
  __shared__ float sout[SOB][304];              // 19456 B
  __shared__ int   rb_s[2][MT];
  __shared__ float scl_s[2][MT];

  const int* wsi = (const int*)wsf;
  const unsigned short* wtg = (const unsigned short*)(wsf + WS_WTG);
  int tid = threadIdx.x;
  int count = wsi[WS_CNT];
  int Mtiles = (count + MT - 1) / MT;
  int kr = blockIdx.x / GMG, g = blockIdx.x % GMG;
  int v0 = kr * KR;
  int klen = NV - v0; if (klen > KR) klen = KR;
  int nch = (klen + 31) >> 5;
  int tpg = (Mtiles + GMG - 1) / GMG;
  int mt0 = g * tpg;
  int mt1 = min(mt0 + tpg, Mtiles);

  int b0 = 0;
  {
    int r0c = mt0 * MT;
    if (r0c < count) b0 = wsi[WS_ROWS + r0c] >> 7;
  }

  // stage A/B slice + zero sout
  for (int q = tid; q < 2 * KR; q += 512) {
    int a = q >> 7, k = q & (KR - 1);
    float val = 0.f;
    if (v0 + k < NV) val = wsf[(a ? WS_B : WS_A) + v0 + k];
    cls[a][k] = val;
  }
  for (int q = tid; q < SOB * 304; q += 512) ((float*)sout)[q] = 0.f;

  int wv = tid >> 6, lane = tid & 63;
  int q4 = lane >> 4, l15 = lane & 15;
  int nt0 = (wv * NTI) >> 3, nt1 = ((wv + 1) * NTI) >> 3;

  // B-fragments direct from WtG (coalesced bf16x8 per fragment)
  bf16x8 bfrag[3][4] = {};
  #pragma unroll
  for (int j = 0; j < 3; ++j)
    #pragma unroll
    for (int c5 = 0; c5 < 4; ++c5)
      if (nt0 + j < nt1 && c5 < nch) {
        int n = (nt0 + j) * 16 + l15;
        bfrag[j][c5] = *(const bf16x8*)(const void*)&wtg[(long)n * WTGLD + v0 + c5 * 32 + q4 * 8];
      }

  // BARRIER: cls/sout staged above are read by stage_write/emit below (round-4 bug #1)
  __syncthreads();

  // staging: slot tid+512j -> (row rm, 4 k's); exactly 1024 slots
  float4 eld[2];
  int    vld[2];
  int    m_row; float m_scl;

  auto stage_load = [&](int mtx, bool valid) {
    int r0 = mtx * MT;
    #pragma unroll
    for (int j = 0; j < 2; ++j) {
      vld[j] = 0;
      int q = tid + j * 512;
      int rm = q >> 5, k = (q & 31) * 4;
      int pos = r0 + rm;
      if (valid && pos < count && k < klen) {
        int rowid = wsi[WS_ROWS + pos];
        eld[j] = *(const float4*)(edge + (long)clist[rowid] * NV + v0 + k);
        vld[j] = 1;
      }
    }
    m_row = -1; m_scl = 0.f;
    if (tid < MT) {
      int pos = r0 + tid;
      if (valid && pos < count) {
        int rowid = wsi[WS_ROWS + pos];
        float S = wsf[WS_S + pos];
        int ln = clen[rowid >> 7];
        m_row = rowid;
        m_scl = 1.0f / (S * (float)(ln > 0 ? ln : 1));
      }
    }
  };

  auto stage_write = [&](int nb) {
    char* eb = (char*)&ebuf[nb][0];
    #pragma unroll
    for (int j = 0; j < 2; ++j) {
      int q = tid + j * 512;
      int rm = q >> 5, k = (q & 31) * 4;
      ushort4 ev = make_ushort4(0, 0, 0, 0);
      if (vld[j]) {
        float4 a = *(const float4*)&cls[0][k];
        float4 b = *(const float4*)&cls[1][k];
        float4 em = eld[j];
        ev.x = f2bf(__expf(fmaf(a.x, em.x, (em.x > 0.f) ? b.x : 0.f)));
        ev.y = f2bf(__expf(fmaf(a.y, em.y, (em.y > 0.f) ? b.y : 0.f)));
        ev.z = f2bf(__expf(fmaf(a.z, em.z, (em.z > 0.f) ? b.z : 0.f)));
        ev.w = f2bf(__expf(fmaf(a.w, em.w, (em.w > 0.f) ? b.w : 0.f)));
      }
      int off = (rm << 8) + (k << 1);
      off ^= (rm & 7) << 4;
      *(ushort4*)(eb + off) = ev;
    }
    if (tid < MT) { rb_s[nb][tid] = m_row; scl_s[nb][tid] = m_scl; }
  };

  // per-lane batch-run accumulator (rows sorted by batch)
  int curb = -1;
  float rs0 = 0.f, rs1 = 0.f, rs2 = 0.f;
  auto emit = [&](int b, float s0, float s1, float s2) {
    if (b < 0) return;
    #pragma unroll
    for (int j = 0; j < 3; ++j) {
      if (nt0 + j < nt1) {
        int n = (nt0 + j) * 16 + l15;
        if (n < ND) {
          float v = (j == 0) ? s0 : (j == 1) ? s1 : s2;
          int rel = b - b0;
          if (rel >= 0 && rel < SOB) atomicAdd(&sout[rel][n], v);
          else atomicAdd(&out[b * ND + n], v);
        }
      }
    }
  };

  if (mt0 < mt1) {
    stage_load(mt0, true);
    stage_write(0);
    __syncthreads();

    int cb = 0;
    for (int mt = mt0; mt < mt1; ++mt) {
      stage_load(mt + 1, mt + 1 < mt1);

      f32x4 acc[2][3] = {};
      const char* eb = (const char*)&ebuf[cb][0];
      #pragma unroll
      for (int c5 = 0; c5 < 4; ++c5) {
        if (c5 < nch) {
          int kb2 = (c5 * 32 + q4 * 8) << 1;
          // round-4 bug #2 fix: add row base + k offset FIRST, then XOR-swizzle
          int off0 = ((l15 << 8) + kb2) ^ ((l15 & 7) << 4);
          int off1 = (((16 + l15) << 8) + kb2) ^ ((l15 & 7) << 4);
          bf16x8 a0 = *(const bf16x8*)(const void*)(eb + off0);
          bf16x8 a1 = *(const bf16x8*)(const void*)(eb + off1);
          #pragma unroll
          for (int j = 0; j < 3; ++j) {
            if (nt0 + j < nt1) {
              acc[0][j] = __builtin_amdgcn_mfma_f32_16x16x32_bf16(a0, bfrag[j][c5], acc[0][j], 0, 0, 0);
              acc[1][j] = __builtin_amdgcn_mfma_f32_16x16x32_bf16(a1, bfrag[j][c5], acc[1][j], 0, 0, 0);
            }
          }
        }
      }

      stage_write(cb ^ 1);

      // fold current tile into per-lane runs (rows ascending: ms then r)
      #pragma unroll
      for (int ms = 0; ms < 2; ++ms)
        #pragma unroll
        for (int r = 0; r < 4; ++r) {
          int m = ms * 16 + q4 * 4 + r;
          int row = rb_s[cb][m];
          if (row >= 0) {
            int b = row >> 7;
            float sc = scl_s[cb][m];
            if (b != curb) {
              emit(curb, rs0, rs1, rs2);
              curb = b; rs0 = rs1 = rs2 = 0.f;
            }
            rs0 += acc[ms][0][r] * sc;
            rs1 += acc[ms][1][r] * sc;
            rs2 += acc[ms][2][r] * sc;
          }
        }

      __syncthreads();
      cb ^= 1;
    }
    emit(curb, rs0, rs1, rs2);
  }
  __syncthreads();

  // final emission: sout -> out (skip zeros)
  for (int q = tid; q < SOB * 304; q += 512) {
    int s = q / 304, n = q - s * 304;
    float v = sout[s][n];
    if (n < ND && v != 0.f) {
      int b = b0 + s;
      if (b < NB) atomicAdd(&out[b * ND + n], v);
    }
  }
}

extern "C" void kernel_launch(void* const* d_in, const int* in_sizes, int n_in,
                              void* d_out, int out_size, void* d_ws, size_t ws_size,
                              hipStream_t stream) {
  const int*   clist = (const int*)d_in[0];
  const int*   clen  = (const int*)d_in[1];
  const float* embed = (const float*)d_in[2];
  const float* cw    = (const float*)d_in[3];
  const float* edge  = (const float*)d_in[4];
  const float* aff   = (const float*)d_in[5];
  const float* lam   = (const float*)d_in[6];
  float* out = (float*)d_out;
  float* wsf = (float*)d_ws;
  int*   wsi = (int*)d_ws;

  hipLaunchKernelGGL(k_init,    dim3(77),          dim3(256), 0, stream, out, wsf);
  hipLaunchKernelGGL(k_context, dim3(NB * CSL),    dim3(320), 0, stream, clist, clen, embed, wsf);
  hipLaunchKernelGGL(k_cn,      dim3(1),           dim3(320), 0, stream, wsf);
  hipLaunchKernelGGL(k_cos,     dim3(NV / 4),      dim3(256), 0, stream, cw, lam, aff, wsf);
  hipLaunchKernelGGL(k_wt,      dim3(WTGLD / 64),  dim3(256), 0, stream, cw, wsf);
  hipLaunchKernelGGL(k_compact, dim3(1),           dim3(256), 0, stream, clen, wsi);
  hipLaunchKernelGGL(k_srow,    dim3(NB * NL / 4), dim3(256), 0, stream, clist, edge, wsf);
  hipLaunchKernelGGL(k_main,    dim3(NKR * GMG),   dim3(512), 0, stream,
                     clist, clen, edge, wsf, out);
}